// Round 8
// baseline (172.764 us; speedup 1.0000x reference)
//
#include <hip/hip_runtime.h>
#include <hip/hip_bf16.h>

#define B_ 8
#define T_ 16
#define D_ 1536
#define N_ 12
#define KH_ 2
#define G_ 6
#define H_ 128
#define S_ 8192
#define NCHUNK 32
#define SPLITS 8

typedef __attribute__((ext_vector_type(8))) short bf16x8;
typedef __attribute__((ext_vector_type(4))) float f32x4;
typedef __attribute__((ext_vector_type(4))) unsigned short u16x4;

__device__ __forceinline__ unsigned short f2bf(float x) {
    unsigned u = __float_as_uint(x);
    u += 0x7fffu + ((u >> 16) & 1u);
    return (unsigned short)(u >> 16);
}
__device__ __forceinline__ float bf2f(unsigned short h) {
    return __uint_as_float(((unsigned)h) << 16);
}

// ---------------------------------------------------------------------------
// Split-K MFMA GEMM with split-bf16 (3-product) accuracy. (unchanged)
// ---------------------------------------------------------------------------
__global__ __launch_bounds__(256, 4) void gemm_splitk(
    const float* __restrict__ A,
    const float* __restrict__ W0, int n0, int ldb0,
    const float* __restrict__ W1, int n1, int ldb1,
    const float* __restrict__ W2, int ldb2,
    float* __restrict__ part, int NTOT, int Kdim)
{
    __shared__ __align__(16) unsigned short Ah[64][40], Al[64][40];
    __shared__ __align__(16) unsigned short Bh[64][40], Bl[64][40];
    const int tid = threadIdx.x;
    const int wave = tid >> 6, lane = tid & 63;
    const int col = lane & 15, g = lane >> 4;
    const int row0 = blockIdx.y * 64;
    const int c0 = blockIdx.x * 64;
    const int ks = Kdim / gridDim.z;
    const int k0 = blockIdx.z * ks;

    const float* Bp; int ldb, bc0;
    if (c0 < n0)           { Bp = W0; ldb = ldb0; bc0 = c0; }
    else if (c0 < n0 + n1) { Bp = W1; ldb = ldb1; bc0 = c0 - n0; }
    else                   { Bp = W2; ldb = ldb2; bc0 = c0 - n0 - n1; }

    f32x4 acc[4];
#pragma unroll
    for (int nt = 0; nt < 4; ++nt) acc[nt] = (f32x4){0.f, 0.f, 0.f, 0.f};

    for (int kk = 0; kk < ks; kk += 32) {
        __syncthreads();
        if (tid < 128) {
#pragma unroll
            for (int c = tid; c < 512; c += 128) {
                int r = c >> 3, k4 = c & 7;
                float4 v = *(const float4*)&A[(size_t)(row0 + r) * Kdim + k0 + kk + k4 * 4];
                float f[4] = {v.x, v.y, v.z, v.w};
                u16x4 hv, lv;
#pragma unroll
                for (int i = 0; i < 4; ++i) {
                    unsigned short hh = f2bf(f[i]);
                    hv[i] = hh; lv[i] = f2bf(f[i] - bf2f(hh));
                }
                *(u16x4*)&Ah[r][k4 * 4] = hv;
                *(u16x4*)&Al[r][k4 * 4] = lv;
            }
        } else {
            int t2 = tid - 128;
            int kq = t2 >> 4, cq = t2 & 15;
            float a[4][4];
#pragma unroll
            for (int r = 0; r < 4; ++r) {
                float4 v = *(const float4*)&Bp[(size_t)(k0 + kk + kq * 4 + r) * ldb + bc0 + cq * 4];
                a[r][0] = v.x; a[r][1] = v.y; a[r][2] = v.z; a[r][3] = v.w;
            }
#pragma unroll
            for (int cc = 0; cc < 4; ++cc) {
                u16x4 hv, lv;
#pragma unroll
                for (int r = 0; r < 4; ++r) {
                    unsigned short hh = f2bf(a[r][cc]);
                    hv[r] = hh; lv[r] = f2bf(a[r][cc] - bf2f(hh));
                }
                *(u16x4*)&Bh[cq * 4 + cc][kq * 4] = hv;
                *(u16x4*)&Bl[cq * 4 + cc][kq * 4] = lv;
            }
        }
        __syncthreads();

        bf16x8 ah = *(const bf16x8*)&Ah[wave * 16 + col][g * 8];
        bf16x8 al = *(const bf16x8*)&Al[wave * 16 + col][g * 8];
#pragma unroll
        for (int nt = 0; nt < 4; ++nt) {
            bf16x8 bh = *(const bf16x8*)&Bh[nt * 16 + col][g * 8];
            bf16x8 bl = *(const bf16x8*)&Bl[nt * 16 + col][g * 8];
            acc[nt] = __builtin_amdgcn_mfma_f32_16x16x32_bf16(ah, bh, acc[nt], 0, 0, 0);
            acc[nt] = __builtin_amdgcn_mfma_f32_16x16x32_bf16(ah, bl, acc[nt], 0, 0, 0);
            acc[nt] = __builtin_amdgcn_mfma_f32_16x16x32_bf16(al, bh, acc[nt], 0, 0, 0);
        }
    }
#pragma unroll
    for (int nt = 0; nt < 4; ++nt)
#pragma unroll
        for (int j = 0; j < 4; ++j) {
            size_t prow = (size_t)blockIdx.z * 128 + row0 + wave * 16 + g * 4 + j;
            part[prow * NTOT + c0 + nt * 16 + col] = acc[nt][j];
        }
}

// ---------------------------------------------------------------------------
// Reduce SPLITS partials + bias + RoPE. (unchanged)
// ---------------------------------------------------------------------------
__global__ __launch_bounds__(256) void rope_reduce(
    const float* __restrict__ part,
    const float* __restrict__ bq, const float* __restrict__ bk,
    const float* __restrict__ bv,
    const int* __restrict__ seg, const int* __restrict__ curp,
    float* __restrict__ q_rope, float* __restrict__ k_new,
    float* __restrict__ v_new)
{
    const int row = blockIdx.x;
    const int b = row >> 4, t = row & 15;
    const int tid = threadIdx.x;
    __shared__ float S[2048];
    __shared__ float sc[64][2];

    const int CUR = curp[0];
    int c = 0;
    for (int tt = 0; tt <= t; ++tt) c += (seg[b * T_ + tt] != 0) ? 1 : 0;
    int pos = max(c - 1, 0) + CUR;

    if (tid < 64) {
        float frac = (2.0f * tid) / (float)H_;
        float ts = expf(frac * logf(1000000.0f));
        float ang = (float)pos / ts;
        sc[tid][0] = sinf(ang);
        sc[tid][1] = cosf(ang);
    }
    for (int e = tid; e < 2048; e += 256) {
        float s = 0.f;
#pragma unroll
        for (int sp = 0; sp < SPLITS; ++sp)
            s += part[((size_t)sp * 128 + row) * 2048 + e];
        S[e] = s;
    }
    __syncthreads();

    for (int e = tid; e < 768; e += 256) {
        int n = e >> 6, i = e & 63;
        float x1 = S[n * 128 + i] + bq[n * 128 + i];
        float x2 = S[n * 128 + i + 64] + bq[n * 128 + i + 64];
        float s = sc[i][0], co = sc[i][1];
        q_rope[(size_t)row * 1536 + n * 128 + i]      = x1 * co - x2 * s;
        q_rope[(size_t)row * 1536 + n * 128 + i + 64] = x2 * co + x1 * s;
    }
    if (tid < 128) {
        int n = tid >> 6, i = tid & 63;
        float x1 = S[1536 + n * 128 + i] + bk[n * 128 + i];
        float x2 = S[1536 + n * 128 + i + 64] + bk[n * 128 + i + 64];
        float s = sc[i][0], co = sc[i][1];
        k_new[(size_t)row * 256 + n * 128 + i]      = x1 * co - x2 * s;
        k_new[(size_t)row * 256 + n * 128 + i + 64] = x2 * co + x1 * s;
    }
    v_new[(size_t)row * 256 + tid] = S[1792 + tid] + bv[tid];
}

// ---------------------------------------------------------------------------
// MFMA flash attention v8: occupancy-first.
// grid = (NCHUNK=32, B, KH) = 512 blocks, 384 thr = 6 waves, slim LDS (27.5K)
// so 2 blocks (12 waves) co-reside per CU and cross-block TLP hides latency.
// K: global -> register B-frags (pairs of float4 per kt-half -> 16 full
//    cachelines per instruction, no overfetch; waves 1-5 hit L1) -> bf16.
// V: global->reg early (T14) -> bf16 transposed LDS write late, dbuf.
// ---------------------------------------------------------------------------
__global__ __launch_bounds__(384) void attn_mfma(
    const float* __restrict__ q_rope, const float* __restrict__ k_new,
    const float* __restrict__ v_new,
    const float* __restrict__ k_cache, const float* __restrict__ v_cache,
    const int* __restrict__ seg, const int* __restrict__ start_ind,
    const int* __restrict__ curp,
    float* __restrict__ part)
{
    const int chunk = blockIdx.x, b = blockIdx.y, kh = blockIdx.z;
    const int tid = threadIdx.x;
    const int wave = tid >> 6, lane = tid & 63;
    const int col = lane & 15, g = lane >> 4;
    const float scale = 0.088388347648318447f;
    const float NEG_INF = -__builtin_inff();

    const int CUR = curp[0];
    const int SPAN = CUR + T_;
    const int CH = (SPAN + NCHUNK - 1) / NCHUNK;
    const int s0 = chunk * CH;
    const int s1 = min(s0 + CH, SPAN);

    int st = start_ind[b];
    if (st < 0) {
        st = 0;
        for (int tt = 0; tt < T_; ++tt)
            if (seg[b * T_ + tt] != 0) { st = tt; break; }
    }

    __shared__ __align__(16) unsigned short Vt[2][128][40];   // 20 KiB (dbuf)
    __shared__ __align__(16) unsigned short Pl[6][16][40];    // 7.5 KiB

    // ---- Q prologue: single-bf16 A-frags, scale folded ----
    const int qbase = wave * 16;
    const int qi_a = qbase + col;
    const int t_a = (qi_a * 171) >> 10;
    const int gh_a = qi_a - t_a * G_;
    const float* qp = &q_rope[(((size_t)b * T_ + t_a) * N_ + kh * G_ + gh_a) * H_];
    bf16x8 qf[4];
#pragma unroll
    for (int ks = 0; ks < 4; ++ks) {
        float4 va = *(const float4*)&qp[ks * 32 + g * 8];
        float4 vb = *(const float4*)&qp[ks * 32 + g * 8 + 4];
        float f[8] = {va.x, va.y, va.z, va.w, vb.x, vb.y, vb.z, vb.w};
        union { bf16x8 v; __hip_bfloat162 h2[4]; } W;
#pragma unroll
        for (int i = 0; i < 4; ++i)
            W.h2[i] = __float22bfloat162_rn(make_float2(f[2 * i] * scale, f[2 * i + 1] * scale));
        qf[ks] = W.v;
    }

    int qpos_r[4], segid_r[4];
#pragma unroll
    for (int j = 0; j < 4; ++j) {
        int qi_c = qbase + g * 4 + j;
        int t_c = (qi_c * 171) >> 10;
        segid_r[j] = seg[b * T_ + t_c];
        qpos_r[j] = CUR + t_c - st;
    }

    float m[4], lsum[4];
#pragma unroll
    for (int j = 0; j < 4; ++j) { m[j] = NEG_INF; lsum[j] = 0.f; }
    f32x4 oacc[8];
#pragma unroll
    for (int nt = 0; nt < 8; ++nt) oacc[nt] = (f32x4){0.f, 0.f, 0.f, 0.f};

    auto krow = [&](int s) -> const float* {
        s = min(s, SPAN - 1);
        return (s < CUR)
            ? &k_cache[((((size_t)b * S_ + s) * KH_) + kh) * H_]
            : &k_new[((((size_t)b * T_ + (s - CUR)) * KH_) + kh) * H_];
    };
    auto vrow = [&](int s) -> const float* {
        s = min(s, SPAN - 1);
        return (s < CUR)
            ? &v_cache[((((size_t)b * S_ + s) * KH_) + kh) * H_]
            : &v_new[((((size_t)b * T_ + (s - CUR)) * KH_) + kh) * H_];
    };

    // ---- V loads into regs (issued early; tid<256: 4 keys x 4 dims) ----
    const int vky4 = tid >> 5, vd4 = tid & 31;
    auto loadV = [&](float4* vreg, int stile) {
        if (tid < 256) {
#pragma unroll
            for (int r = 0; r < 4; ++r)
                vreg[r] = *(const float4*)(vrow(stile + vky4 * 4 + r) + vd4 * 4);
        }
    };
    // ---- V convert + transposed write (after compute, before barrier) ----
    auto writeV = [&](int bufi, const float4* vreg) {
        if (tid < 256) {
            float a[4][4];
#pragma unroll
            for (int r = 0; r < 4; ++r) {
                a[r][0] = vreg[r].x; a[r][1] = vreg[r].y;
                a[r][2] = vreg[r].z; a[r][3] = vreg[r].w;
            }
#pragma unroll
            for (int dd = 0; dd < 4; ++dd) {
                u16x4 hv;
#pragma unroll
                for (int r = 0; r < 4; ++r) hv[r] = f2bf(a[r][dd]);
                *(u16x4*)&Vt[bufi][vd4 * 4 + dd][vky4 * 4] = hv;
            }
        }
    };

    auto computeTile = [&](int bufi, int stile) {
        // ---- K: global -> regs (coalesced pairs), convert, 8 MFMAs ----
        const float* kr0 = krow(stile + col);
        const float* kr1 = krow(stile + 16 + col);
        float4 kfa[8], kfb[8];
#pragma unroll
        for (int ks = 0; ks < 4; ++ks) {
            kfa[ks * 2 + 0] = *(const float4*)(kr0 + ks * 32 + g * 8);
            kfa[ks * 2 + 1] = *(const float4*)(kr0 + ks * 32 + g * 8 + 4);
            kfb[ks * 2 + 0] = *(const float4*)(kr1 + ks * 32 + g * 8);
            kfb[ks * 2 + 1] = *(const float4*)(kr1 + ks * 32 + g * 8 + 4);
        }
        f32x4 sacc0 = {0.f, 0.f, 0.f, 0.f}, sacc1 = {0.f, 0.f, 0.f, 0.f};
#pragma unroll
        for (int ks = 0; ks < 4; ++ks) {
            float fa[8] = {kfa[ks*2].x, kfa[ks*2].y, kfa[ks*2].z, kfa[ks*2].w,
                           kfa[ks*2+1].x, kfa[ks*2+1].y, kfa[ks*2+1].z, kfa[ks*2+1].w};
            float fb[8] = {kfb[ks*2].x, kfb[ks*2].y, kfb[ks*2].z, kfb[ks*2].w,
                           kfb[ks*2+1].x, kfb[ks*2+1].y, kfb[ks*2+1].z, kfb[ks*2+1].w};
            union { bf16x8 v; __hip_bfloat162 h2[4]; } Wa, Wb;
#pragma unroll
            for (int i = 0; i < 4; ++i) {
                Wa.h2[i] = __float22bfloat162_rn(make_float2(fa[2 * i], fa[2 * i + 1]));
                Wb.h2[i] = __float22bfloat162_rn(make_float2(fb[2 * i], fb[2 * i + 1]));
            }
            sacc0 = __builtin_amdgcn_mfma_f32_16x16x32_bf16(qf[ks], Wa.v, sacc0, 0, 0, 0);
            sacc1 = __builtin_amdgcn_mfma_f32_16x16x32_bf16(qf[ks], Wb.v, sacc1, 0, 0, 0);
        }

        // ---- mask + online softmax ----
        float rj[4];
        const int skey0 = stile + col, skey1 = stile + 16 + col;
#pragma unroll
        for (int j = 0; j < 4; ++j) {
            bool v0 = (skey0 < s1) && (skey0 - st <= qpos_r[j]) &&
                      (((skey0 >= st) ? 1 : 0) == segid_r[j]);
            bool v1 = (skey1 < s1) && (skey1 - st <= qpos_r[j]) &&
                      (((skey1 >= st) ? 1 : 0) == segid_r[j]);
            float lg0 = v0 ? sacc0[j] : NEG_INF;
            float lg1 = v1 ? sacc1[j] : NEG_INF;
            float tm = fmaxf(lg0, lg1);
            tm = fmaxf(tm, __shfl_xor(tm, 1));
            tm = fmaxf(tm, __shfl_xor(tm, 2));
            tm = fmaxf(tm, __shfl_xor(tm, 4));
            tm = fmaxf(tm, __shfl_xor(tm, 8));
            float mn = fmaxf(m[j], tm);
            float r, p0, p1;
            if (mn == NEG_INF) { r = 1.f; p0 = 0.f; p1 = 0.f; }
            else {
                r  = __expf(m[j] - mn);
                p0 = __expf(lg0 - mn);
                p1 = __expf(lg1 - mn);
            }
            float ps = p0 + p1;
            ps += __shfl_xor(ps, 1);
            ps += __shfl_xor(ps, 2);
            ps += __shfl_xor(ps, 4);
            ps += __shfl_xor(ps, 8);
            lsum[j] = lsum[j] * r + ps;
            m[j] = mn;
            rj[j] = r;
            int row = g * 4 + j;
            Pl[wave][row][col]      = f2bf(p0);
            Pl[wave][row][16 + col] = f2bf(p1);
        }

#pragma unroll
        for (int nt = 0; nt < 8; ++nt) {
#pragma unroll
            for (int j = 0; j < 4; ++j) oacc[nt][j] *= rj[j];
        }

        // ---- PV ----
        bf16x8 pa = *(const bf16x8*)&Pl[wave][col][g * 8];
#pragma unroll
        for (int nt = 0; nt < 8; ++nt) {
            bf16x8 vb = *(const bf16x8*)&Vt[bufi][nt * 16 + col][g * 8];
            oacc[nt] = __builtin_amdgcn_mfma_f32_16x16x32_bf16(pa, vb, oacc[nt], 0, 0, 0);
        }
    };

    // ---- prologue: V for tile 0 into buffer 0 ----
    const int ntiles = (s1 - s0 + 31) >> 5;
    float4 vA[4], vB[4];
    loadV(vA, s0);
    writeV(0, vA);
    __syncthreads();

    // ---- 2-phase main loop ----
    for (int ti = 0; ti < ntiles; ti += 2) {
        // phase 0: compute buf0 @ tile ti; prepare buf1 @ tile ti+1
        if (ti + 1 < ntiles) loadV(vB, s0 + (ti + 1) * 32);
        computeTile(0, s0 + ti * 32);
        if (ti + 1 < ntiles) writeV(1, vB);
        __syncthreads();
        // phase 1: compute buf1 @ tile ti+1; prepare buf0 @ tile ti+2
        if (ti + 1 < ntiles) {
            if (ti + 2 < ntiles) loadV(vA, s0 + (ti + 2) * 32);
            computeTile(1, s0 + (ti + 1) * 32);
            if (ti + 2 < ntiles) writeV(0, vA);
            __syncthreads();
        }
    }

    // ---- write partials ----
    const size_t base_q = (((size_t)chunk * B_ + b) * KH_ + kh) * 96;
#pragma unroll
    for (int j = 0; j < 4; ++j) {
        int qi = qbase + g * 4 + j;
        size_t pb = (base_q + qi) * 132;
        if (col == 0) { part[pb] = m[j]; part[pb + 1] = lsum[j]; }
#pragma unroll
        for (int nt = 0; nt < 8; ++nt)
            part[pb + 2 + nt * 16 + col] = oacc[nt][j];
    }
}

// ---------------------------------------------------------------------------
// Combine per-chunk partials -> qkv (b,t,N,H)
// ---------------------------------------------------------------------------
__global__ __launch_bounds__(256) void combine_kernel(
    const float* __restrict__ part, float* __restrict__ qkv)
{
    const int row = blockIdx.x;
    const int b = row >> 4, t = row & 15;
    const int tid = threadIdx.x;
    const int half = tid >> 7, h = tid & 127;
    const size_t cstride = (size_t)B_ * KH_ * 96 * 132;

    for (int nb = 0; nb < N_; nb += 2) {
        int n = nb + half;
        int kh = n / G_, g = n - kh * G_;
        int qi = t * G_ + g;
        size_t base0 = (((size_t)b * KH_ + kh) * 96 + qi) * 132;
        float M = -__builtin_inff();
        for (int c = 0; c < NCHUNK; ++c)
            M = fmaxf(M, part[base0 + c * cstride]);
        float den = 0.f, num = 0.f;
        for (int c = 0; c < NCHUNK; ++c) {
            float mc = part[base0 + c * cstride];
            float e = (M == -__builtin_inff() || mc == -__builtin_inff())
                          ? 0.f : expf(mc - M);
            den += e * part[base0 + c * cstride + 1];
            num += e * part[base0 + c * cstride + 2 + h];
        }
        qkv[(size_t)row * (N_ * H_) + n * H_ + h] = (den > 0.f) ? num / den : 0.f;
    }
}

// ---------------------------------------------------------------------------
__global__ __launch_bounds__(256) void sum_reduce(
    const float* __restrict__ part, float* __restrict__ out, int n)
{
    int i = blockIdx.x * 256 + threadIdx.x;
    if (i < n) {
        float s = 0.f;
#pragma unroll
        for (int sp = 0; sp < SPLITS; ++sp) s += part[(size_t)sp * n + i];
        out[i] = s;
    }
}

// ---------------------------------------------------------------------------
extern "C" void kernel_launch(void* const* d_in, const int* in_sizes, int n_in,
                              void* d_out, int out_size, void* d_ws, size_t ws_size,
                              hipStream_t stream)
{
    (void)in_sizes; (void)n_in; (void)out_size; (void)ws_size;
    const float* x       = (const float*)d_in[0];
    const float* k_cache = (const float*)d_in[1];
    const float* v_cache = (const float*)d_in[2];
    const float* wq      = (const float*)d_in[3];
    const float* bq      = (const float*)d_in[4];
    const float* wk      = (const float*)d_in[5];
    const float* bk      = (const float*)d_in[6];
    const float* wv      = (const float*)d_in[7];
    const float* bv      = (const float*)d_in[8];
    const float* wo      = (const float*)d_in[9];
    const int*   seg     = (const int*)d_in[10];
    const int*   start_i = (const int*)d_in[11];
    const int*   curp    = (const int*)d_in[12];
    float* out = (float*)d_out;
    float* ws  = (float*)d_ws;

    // aliased region: projection partials (2,097,152 floats) and attention
    // partials (NCHUNK*B*KH*96*132 = 6,488,064 floats); lifetimes disjoint.
    const size_t PSZ  = (size_t)NCHUNK * B_ * KH_ * 96 * 132; // 6,488,064
    const size_t QSZ  = (size_t)B_ * T_ * N_ * H_;            // 196,608
    const size_t KSZ  = (size_t)B_ * T_ * KH_ * H_;           // 32,768
    float* partP  = ws;
    float* partA  = ws;
    float* q_rope = ws + PSZ;
    float* k_new  = q_rope + QSZ;
    float* v_new  = k_new + KSZ;
    float* qkv    = v_new + KSZ;

    gemm_splitk<<<dim3(32, 2, SPLITS), 256, 0, stream>>>(
        x, wq, 1536, 1536, wk, 256, 256, wv, 256, partP, 2048, D_);

    rope_reduce<<<B_ * T_, 256, 0, stream>>>(partP, bq, bk, bv, seg, curp,
                                             q_rope, k_new, v_new);

    attn_mfma<<<dim3(NCHUNK, B_, KH_), 384, 0, stream>>>(
        q_rope, k_new, v_new, k_cache, v_cache, seg, start_i, curp, partA);

    combine_kernel<<<B_ * T_, 256, 0, stream>>>(partA, qkv);

    gemm_splitk<<<dim3(24, 2, SPLITS), 256, 0, stream>>>(
        qkv, wo, 1536, 1536, wo, 0, 1536, wo, 1536, partP, 1536, N_ * H_);

    sum_reduce<<<(B_ * T_ * D_ + 255) / 256, 256, 0, stream>>>(
        partP, out, B_ * T_ * D_);
}

// Round 9
// 156.298 us; speedup vs baseline: 1.1054x; 1.1054x over previous
//
#include <hip/hip_runtime.h>
#include <hip/hip_bf16.h>

#define B_ 8
#define T_ 16
#define D_ 1536
#define N_ 12
#define KH_ 2
#define G_ 6
#define H_ 128
#define S_ 8192
#define NCHUNK 24
#define SPLITS 8
#define SKV 4160   // padded key stride for packed KV (requires CUR+T <= 4160)

typedef __attribute__((ext_vector_type(8))) short bf16x8;
typedef __attribute__((ext_vector_type(4))) float f32x4;
typedef __attribute__((ext_vector_type(4))) unsigned short u16x4;

__device__ __forceinline__ unsigned short f2bf(float x) {
    unsigned u = __float_as_uint(x);
    u += 0x7fffu + ((u >> 16) & 1u);
    return (unsigned short)(u >> 16);
}
__device__ __forceinline__ float bf2f(unsigned short h) {
    return __uint_as_float(((unsigned)h) << 16);
}

// ---------------------------------------------------------------------------
// Split-K MFMA GEMM with split-bf16 (3-product) accuracy. (unchanged)
// ---------------------------------------------------------------------------
__global__ __launch_bounds__(256, 4) void gemm_splitk(
    const float* __restrict__ A,
    const float* __restrict__ W0, int n0, int ldb0,
    const float* __restrict__ W1, int n1, int ldb1,
    const float* __restrict__ W2, int ldb2,
    float* __restrict__ part, int NTOT, int Kdim)
{
    __shared__ __align__(16) unsigned short Ah[64][40], Al[64][40];
    __shared__ __align__(16) unsigned short Bh[64][40], Bl[64][40];
    const int tid = threadIdx.x;
    const int wave = tid >> 6, lane = tid & 63;
    const int col = lane & 15, g = lane >> 4;
    const int row0 = blockIdx.y * 64;
    const int c0 = blockIdx.x * 64;
    const int ks = Kdim / gridDim.z;
    const int k0 = blockIdx.z * ks;

    const float* Bp; int ldb, bc0;
    if (c0 < n0)           { Bp = W0; ldb = ldb0; bc0 = c0; }
    else if (c0 < n0 + n1) { Bp = W1; ldb = ldb1; bc0 = c0 - n0; }
    else                   { Bp = W2; ldb = ldb2; bc0 = c0 - n0 - n1; }

    f32x4 acc[4];
#pragma unroll
    for (int nt = 0; nt < 4; ++nt) acc[nt] = (f32x4){0.f, 0.f, 0.f, 0.f};

    for (int kk = 0; kk < ks; kk += 32) {
        __syncthreads();
        if (tid < 128) {
#pragma unroll
            for (int c = tid; c < 512; c += 128) {
                int r = c >> 3, k4 = c & 7;
                float4 v = *(const float4*)&A[(size_t)(row0 + r) * Kdim + k0 + kk + k4 * 4];
                float f[4] = {v.x, v.y, v.z, v.w};
                u16x4 hv, lv;
#pragma unroll
                for (int i = 0; i < 4; ++i) {
                    unsigned short hh = f2bf(f[i]);
                    hv[i] = hh; lv[i] = f2bf(f[i] - bf2f(hh));
                }
                *(u16x4*)&Ah[r][k4 * 4] = hv;
                *(u16x4*)&Al[r][k4 * 4] = lv;
            }
        } else {
            int t2 = tid - 128;
            int kq = t2 >> 4, cq = t2 & 15;
            float a[4][4];
#pragma unroll
            for (int r = 0; r < 4; ++r) {
                float4 v = *(const float4*)&Bp[(size_t)(k0 + kk + kq * 4 + r) * ldb + bc0 + cq * 4];
                a[r][0] = v.x; a[r][1] = v.y; a[r][2] = v.z; a[r][3] = v.w;
            }
#pragma unroll
            for (int cc = 0; cc < 4; ++cc) {
                u16x4 hv, lv;
#pragma unroll
                for (int r = 0; r < 4; ++r) {
                    unsigned short hh = f2bf(a[r][cc]);
                    hv[r] = hh; lv[r] = f2bf(a[r][cc] - bf2f(hh));
                }
                *(u16x4*)&Bh[cq * 4 + cc][kq * 4] = hv;
                *(u16x4*)&Bl[cq * 4 + cc][kq * 4] = lv;
            }
        }
        __syncthreads();

        bf16x8 ah = *(const bf16x8*)&Ah[wave * 16 + col][g * 8];
        bf16x8 al = *(const bf16x8*)&Al[wave * 16 + col][g * 8];
#pragma unroll
        for (int nt = 0; nt < 4; ++nt) {
            bf16x8 bh = *(const bf16x8*)&Bh[nt * 16 + col][g * 8];
            bf16x8 bl = *(const bf16x8*)&Bl[nt * 16 + col][g * 8];
            acc[nt] = __builtin_amdgcn_mfma_f32_16x16x32_bf16(ah, bh, acc[nt], 0, 0, 0);
            acc[nt] = __builtin_amdgcn_mfma_f32_16x16x32_bf16(ah, bl, acc[nt], 0, 0, 0);
            acc[nt] = __builtin_amdgcn_mfma_f32_16x16x32_bf16(al, bh, acc[nt], 0, 0, 0);
        }
    }
#pragma unroll
    for (int nt = 0; nt < 4; ++nt)
#pragma unroll
        for (int j = 0; j < 4; ++j) {
            size_t prow = (size_t)blockIdx.z * 128 + row0 + wave * 16 + g * 4 + j;
            part[prow * NTOT + c0 + nt * 16 + col] = acc[nt][j];
        }
}

// ---------------------------------------------------------------------------
// Reduce SPLITS partials + bias + RoPE. (unchanged)
// ---------------------------------------------------------------------------
__global__ __launch_bounds__(256) void rope_reduce(
    const float* __restrict__ part,
    const float* __restrict__ bq, const float* __restrict__ bk,
    const float* __restrict__ bv,
    const int* __restrict__ seg, const int* __restrict__ curp,
    float* __restrict__ q_rope, float* __restrict__ k_new,
    float* __restrict__ v_new)
{
    const int row = blockIdx.x;
    const int b = row >> 4, t = row & 15;
    const int tid = threadIdx.x;
    __shared__ float S[2048];
    __shared__ float sc[64][2];

    const int CUR = curp[0];
    int c = 0;
    for (int tt = 0; tt <= t; ++tt) c += (seg[b * T_ + tt] != 0) ? 1 : 0;
    int pos = max(c - 1, 0) + CUR;

    if (tid < 64) {
        float frac = (2.0f * tid) / (float)H_;
        float ts = expf(frac * logf(1000000.0f));
        float ang = (float)pos / ts;
        sc[tid][0] = sinf(ang);
        sc[tid][1] = cosf(ang);
    }
    for (int e = tid; e < 2048; e += 256) {
        float s = 0.f;
#pragma unroll
        for (int sp = 0; sp < SPLITS; ++sp)
            s += part[((size_t)sp * 128 + row) * 2048 + e];
        S[e] = s;
    }
    __syncthreads();

    for (int e = tid; e < 768; e += 256) {
        int n = e >> 6, i = e & 63;
        float x1 = S[n * 128 + i] + bq[n * 128 + i];
        float x2 = S[n * 128 + i + 64] + bq[n * 128 + i + 64];
        float s = sc[i][0], co = sc[i][1];
        q_rope[(size_t)row * 1536 + n * 128 + i]      = x1 * co - x2 * s;
        q_rope[(size_t)row * 1536 + n * 128 + i + 64] = x2 * co + x1 * s;
    }
    if (tid < 128) {
        int n = tid >> 6, i = tid & 63;
        float x1 = S[1536 + n * 128 + i] + bk[n * 128 + i];
        float x2 = S[1536 + n * 128 + i + 64] + bk[n * 128 + i + 64];
        float s = sc[i][0], co = sc[i][1];
        k_new[(size_t)row * 256 + n * 128 + i]      = x1 * co - x2 * s;
        k_new[(size_t)row * 256 + n * 128 + i + 64] = x2 * co + x1 * s;
    }
    v_new[(size_t)row * 256 + tid] = S[1792 + tid] + bv[tid];
}

// ---------------------------------------------------------------------------
// Pack KV to bf16 once: Kb[b][kh][s][128] and Vtb[b][kh][d][s] (transposed).
// Pure streaming pre-pass; removes all conversion/transpose from attention.
// grid = (SKV/32, B, KH), 256 threads. Pad rows clamp to SPAN-1 (masked later).
// ---------------------------------------------------------------------------
__global__ __launch_bounds__(256) void pack_kv(
    const float* __restrict__ k_cache, const float* __restrict__ v_cache,
    const float* __restrict__ k_new, const float* __restrict__ v_new,
    const int* __restrict__ curp,
    unsigned short* __restrict__ Kb, unsigned short* __restrict__ Vtb)
{
    const int tile = blockIdx.x, b = blockIdx.y, kh = blockIdx.z;
    const int tid = threadIdx.x;
    const int CUR = curp[0], SPAN = CUR + T_;
    __shared__ float Vs[32][132];          // +4 pad: transpose reads 2-way only
    const int s_base = tile * 32;
    const int rr = tid >> 5, d0 = (tid & 31) * 4;
    const size_t kout = ((size_t)(b * KH_ + kh) * SKV + s_base) * H_;

#pragma unroll
    for (int i = 0; i < 4; ++i) {
        int r = rr + 8 * i;
        int s = min(s_base + r, SPAN - 1);
        const float* kr = (s < CUR)
            ? &k_cache[(((size_t)b * S_ + s) * KH_ + kh) * H_]
            : &k_new[(((size_t)b * T_ + (s - CUR)) * KH_ + kh) * H_];
        const float* vr = (s < CUR)
            ? &v_cache[(((size_t)b * S_ + s) * KH_ + kh) * H_]
            : &v_new[(((size_t)b * T_ + (s - CUR)) * KH_ + kh) * H_];
        float4 kv = *(const float4*)(kr + d0);
        u16x4 hk;
        hk[0] = f2bf(kv.x); hk[1] = f2bf(kv.y); hk[2] = f2bf(kv.z); hk[3] = f2bf(kv.w);
        *(u16x4*)&Kb[kout + (size_t)r * H_ + d0] = hk;
        *(float4*)&Vs[r][d0] = *(const float4*)(vr + d0);
    }
    __syncthreads();

    const int d = tid >> 1, kq = (tid & 1) * 16;
    unsigned short o[16];
#pragma unroll
    for (int i = 0; i < 16; ++i) o[i] = f2bf(Vs[kq + i][d]);
    unsigned short* vp = &Vtb[((size_t)(b * KH_ + kh) * H_ + d) * SKV + s_base + kq];
#pragma unroll
    for (int i = 0; i < 4; ++i)
        *(u16x4*)(vp + i * 4) = *(u16x4*)&o[i * 4];
}

// ---------------------------------------------------------------------------
// MFMA flash attention v9: barrier-free, LDS-free (except 5 KB P relayout).
// grid = (NCHUNK=24, B, KH*2 q-halves) = 768 blocks, 256 thr = 4 waves.
// Wave owns 16 q-slots (qbase = half*64 + wave*16; slots >= 96 are padding,
// computed on clamped data, never written). K/V MFMA fragments load DIRECTLY
// from packed bf16 global (16B/lane); K double-buffered in named registers.
// ---------------------------------------------------------------------------
__global__ __launch_bounds__(256, 3) void attn_mfma(
    const float* __restrict__ q_rope,
    const unsigned short* __restrict__ Kb,
    const unsigned short* __restrict__ Vtb,
    const int* __restrict__ seg, const int* __restrict__ start_ind,
    const int* __restrict__ curp,
    float* __restrict__ part)
{
    const int chunk = blockIdx.x, b = blockIdx.y;
    const int kh = blockIdx.z >> 1, half = blockIdx.z & 1;
    const int tid = threadIdx.x;
    const int wave = tid >> 6, lane = tid & 63;
    const int col = lane & 15, g = lane >> 4;
    const float scale = 0.088388347648318447f;
    const float NEG_INF = -__builtin_inff();

    const int CUR = curp[0];
    const int SPAN = CUR + T_;
    const int CH = (SPAN + NCHUNK - 1) / NCHUNK;
    const int s0 = chunk * CH;
    const int s1 = min(s0 + CH, SPAN);

    int st = start_ind[b];
    if (st < 0) {
        st = 0;
        for (int tt = 0; tt < T_; ++tt)
            if (seg[b * T_ + tt] != 0) { st = tt; break; }
    }

    __shared__ __align__(16) unsigned short Pl[4][16][40];    // 5 KiB

    // ---- Q prologue: single-bf16 A-frags, scale folded, clamped q-slot ----
    const int qbase = half * 64 + wave * 16;
    const int qi_a = min(qbase + col, 95);
    const int t_a = (qi_a * 171) >> 10;
    const int gh_a = qi_a - t_a * G_;
    const float* qp = &q_rope[(((size_t)b * T_ + t_a) * N_ + kh * G_ + gh_a) * H_];
    bf16x8 qf[4];
#pragma unroll
    for (int ks = 0; ks < 4; ++ks) {
        float4 va = *(const float4*)&qp[ks * 32 + g * 8];
        float4 vb = *(const float4*)&qp[ks * 32 + g * 8 + 4];
        float f[8] = {va.x, va.y, va.z, va.w, vb.x, vb.y, vb.z, vb.w};
        union { bf16x8 v; __hip_bfloat162 h2[4]; } W;
#pragma unroll
        for (int i = 0; i < 4; ++i)
            W.h2[i] = __float22bfloat162_rn(make_float2(f[2 * i] * scale, f[2 * i + 1] * scale));
        qf[ks] = W.v;
    }

    int qpos_r[4], segid_r[4];
    bool wrow[4];
#pragma unroll
    for (int j = 0; j < 4; ++j) {
        int qi_raw = qbase + g * 4 + j;
        wrow[j] = (qi_raw < 96);
        int qi_c = min(qi_raw, 95);
        int t_c = (qi_c * 171) >> 10;
        segid_r[j] = seg[b * T_ + t_c];
        qpos_r[j] = CUR + t_c - st;
    }

    float m[4], lsum[4];
#pragma unroll
    for (int j = 0; j < 4; ++j) { m[j] = NEG_INF; lsum[j] = 0.f; }
    f32x4 oacc[8];
#pragma unroll
    for (int nt = 0; nt < 8; ++nt) oacc[nt] = (f32x4){0.f, 0.f, 0.f, 0.f};

    const unsigned short* Kbase = Kb + (size_t)(b * KH_ + kh) * SKV * H_;
    const unsigned short* Vbase = Vtb + (size_t)(b * KH_ + kh) * H_ * SKV;

    auto loadK = [&](bf16x8* kf, int stile) {
#pragma unroll
        for (int kt = 0; kt < 2; ++kt)
#pragma unroll
            for (int ks = 0; ks < 4; ++ks)
                kf[kt * 4 + ks] = *(const bf16x8*)
                    &Kbase[(size_t)(stile + kt * 16 + col) * H_ + ks * 32 + g * 8];
    };

    auto computeTile = [&](const bf16x8* kf, int stile) {
        f32x4 sacc0 = {0.f, 0.f, 0.f, 0.f}, sacc1 = {0.f, 0.f, 0.f, 0.f};
#pragma unroll
        for (int ks = 0; ks < 4; ++ks) {
            sacc0 = __builtin_amdgcn_mfma_f32_16x16x32_bf16(qf[ks], kf[ks], sacc0, 0, 0, 0);
            sacc1 = __builtin_amdgcn_mfma_f32_16x16x32_bf16(qf[ks], kf[4 + ks], sacc1, 0, 0, 0);
        }

        float rj[4];
        const int skey0 = stile + col, skey1 = stile + 16 + col;
#pragma unroll
        for (int j = 0; j < 4; ++j) {
            bool v0 = (skey0 < s1) && (skey0 - st <= qpos_r[j]) &&
                      (((skey0 >= st) ? 1 : 0) == segid_r[j]);
            bool v1 = (skey1 < s1) && (skey1 - st <= qpos_r[j]) &&
                      (((skey1 >= st) ? 1 : 0) == segid_r[j]);
            float lg0 = v0 ? sacc0[j] : NEG_INF;
            float lg1 = v1 ? sacc1[j] : NEG_INF;
            float tm = fmaxf(lg0, lg1);
            tm = fmaxf(tm, __shfl_xor(tm, 1));
            tm = fmaxf(tm, __shfl_xor(tm, 2));
            tm = fmaxf(tm, __shfl_xor(tm, 4));
            tm = fmaxf(tm, __shfl_xor(tm, 8));
            float mn = fmaxf(m[j], tm);
            float r, p0, p1;
            if (mn == NEG_INF) { r = 1.f; p0 = 0.f; p1 = 0.f; }
            else {
                r  = __expf(m[j] - mn);
                p0 = __expf(lg0 - mn);
                p1 = __expf(lg1 - mn);
            }
            float ps = p0 + p1;
            ps += __shfl_xor(ps, 1);
            ps += __shfl_xor(ps, 2);
            ps += __shfl_xor(ps, 4);
            ps += __shfl_xor(ps, 8);
            lsum[j] = lsum[j] * r + ps;
            m[j] = mn;
            rj[j] = r;
            int row = g * 4 + j;
            Pl[wave][row][col]      = f2bf(p0);
            Pl[wave][row][16 + col] = f2bf(p1);
        }

#pragma unroll
        for (int nt = 0; nt < 8; ++nt) {
#pragma unroll
            for (int j = 0; j < 4; ++j) oacc[nt][j] *= rj[j];
        }

        bf16x8 pa = *(const bf16x8*)&Pl[wave][col][g * 8];
#pragma unroll
        for (int nt = 0; nt < 8; ++nt) {
            bf16x8 vb = *(const bf16x8*)
                &Vbase[(size_t)(nt * 16 + col) * SKV + stile + g * 8];
            oacc[nt] = __builtin_amdgcn_mfma_f32_16x16x32_bf16(pa, vb, oacc[nt], 0, 0, 0);
        }
    };

    // ---- barrier-free main loop, K dbuf in named registers ----
    const int ntiles = (s1 - s0 + 31) >> 5;
    bf16x8 kfA[8], kfB[8];
    loadK(kfA, s0);
    for (int ti = 0; ti < ntiles; ti += 2) {
        if (ti + 1 < ntiles) loadK(kfB, s0 + (ti + 1) * 32);
        computeTile(kfA, s0 + ti * 32);
        if (ti + 1 < ntiles) {
            if (ti + 2 < ntiles) loadK(kfA, s0 + (ti + 2) * 32);
            computeTile(kfB, s0 + (ti + 1) * 32);
        }
    }

    // ---- write partials (real queries only) ----
    const size_t base_q = (((size_t)chunk * B_ + b) * KH_ + kh) * 96;
#pragma unroll
    for (int j = 0; j < 4; ++j) {
        if (!wrow[j]) continue;
        int qi = qbase + g * 4 + j;
        size_t pb = (base_q + qi) * 132;
        if (col == 0) { part[pb] = m[j]; part[pb + 1] = lsum[j]; }
#pragma unroll
        for (int nt = 0; nt < 8; ++nt)
            part[pb + 2 + nt * 16 + col] = oacc[nt][j];
    }
}

// ---------------------------------------------------------------------------
// Combine per-chunk partials -> qkv (b,t,N,H)
// ---------------------------------------------------------------------------
__global__ __launch_bounds__(256) void combine_kernel(
    const float* __restrict__ part, float* __restrict__ qkv)
{
    const int row = blockIdx.x;
    const int b = row >> 4, t = row & 15;
    const int tid = threadIdx.x;
    const int half = tid >> 7, h = tid & 127;
    const size_t cstride = (size_t)B_ * KH_ * 96 * 132;

    for (int nb = 0; nb < N_; nb += 2) {
        int n = nb + half;
        int kh = n / G_, g = n - kh * G_;
        int qi = t * G_ + g;
        size_t base0 = (((size_t)b * KH_ + kh) * 96 + qi) * 132;
        float M = -__builtin_inff();
        for (int c = 0; c < NCHUNK; ++c)
            M = fmaxf(M, part[base0 + c * cstride]);
        float den = 0.f, num = 0.f;
        for (int c = 0; c < NCHUNK; ++c) {
            float mc = part[base0 + c * cstride];
            float e = (M == -__builtin_inff() || mc == -__builtin_inff())
                          ? 0.f : expf(mc - M);
            den += e * part[base0 + c * cstride + 1];
            num += e * part[base0 + c * cstride + 2 + h];
        }
        qkv[(size_t)row * (N_ * H_) + n * H_ + h] = (den > 0.f) ? num / den : 0.f;
    }
}

// ---------------------------------------------------------------------------
__global__ __launch_bounds__(256) void sum_reduce(
    const float* __restrict__ part, float* __restrict__ out, int n)
{
    int i = blockIdx.x * 256 + threadIdx.x;
    if (i < n) {
        float s = 0.f;
#pragma unroll
        for (int sp = 0; sp < SPLITS; ++sp) s += part[(size_t)sp * n + i];
        out[i] = s;
    }
}

// ---------------------------------------------------------------------------
extern "C" void kernel_launch(void* const* d_in, const int* in_sizes, int n_in,
                              void* d_out, int out_size, void* d_ws, size_t ws_size,
                              hipStream_t stream)
{
    (void)in_sizes; (void)n_in; (void)out_size; (void)ws_size;
    const float* x       = (const float*)d_in[0];
    const float* k_cache = (const float*)d_in[1];
    const float* v_cache = (const float*)d_in[2];
    const float* wq      = (const float*)d_in[3];
    const float* bq      = (const float*)d_in[4];
    const float* wk      = (const float*)d_in[5];
    const float* bk      = (const float*)d_in[6];
    const float* wv      = (const float*)d_in[7];
    const float* bv      = (const float*)d_in[8];
    const float* wo      = (const float*)d_in[9];
    const int*   seg     = (const int*)d_in[10];
    const int*   start_i = (const int*)d_in[11];
    const int*   curp    = (const int*)d_in[12];
    float* out = (float*)d_out;
    float* ws  = (float*)d_ws;

    // ws layout (floats unless noted):
    //   [0, PSZ)      projection partials (2,097,152) / attn partials alias
    //   then q_rope, k_new, v_new, qkv
    //   then packed KV as ushort: Kb + Vtb (2 x 8,517,120 ushorts = 34.1 MB)
    const size_t PSZ  = (size_t)NCHUNK * B_ * KH_ * 96 * 132; // 4,866,048
    const size_t QSZ  = (size_t)B_ * T_ * N_ * H_;            // 196,608
    const size_t KSZ  = (size_t)B_ * T_ * KH_ * H_;           // 32,768
    float* partP  = ws;
    float* partA  = ws;
    float* q_rope = ws + PSZ;
    float* k_new  = q_rope + QSZ;
    float* v_new  = k_new + KSZ;
    float* qkv    = v_new + KSZ;
    unsigned short* kvb = (unsigned short*)(qkv + QSZ);
    unsigned short* Kb  = kvb;
    unsigned short* Vtb = kvb + (size_t)B_ * KH_ * SKV * H_;  // 8,517,120

    gemm_splitk<<<dim3(32, 2, SPLITS), 256, 0, stream>>>(
        x, wq, 1536, 1536, wk, 256, 256, wv, 256, partP, 2048, D_);

    rope_reduce<<<B_ * T_, 256, 0, stream>>>(partP, bq, bk, bv, seg, curp,
                                             q_rope, k_new, v_new);

    pack_kv<<<dim3(SKV / 32, B_, KH_), 256, 0, stream>>>(
        k_cache, v_cache, k_new, v_new, curp, Kb, Vtb);

    attn_mfma<<<dim3(NCHUNK, B_, KH_ * 2), 256, 0, stream>>>(
        q_rope, Kb, Vtb, seg, start_i, curp, partA);

    combine_kernel<<<B_ * T_, 256, 0, stream>>>(partA, qkv);

    gemm_splitk<<<dim3(24, 2, SPLITS), 256, 0, stream>>>(
        qkv, wo, 1536, 1536, wo, 0, 1536, wo, 1536, partP, 1536, N_ * H_);

    sum_reduce<<<(B_ * T_ * D_ + 255) / 256, 256, 0, stream>>>(
        partP, out, B_ * T_ * D_);
}

// Round 10
// 112.266 us; speedup vs baseline: 1.5389x; 1.3922x over previous
//
#include <hip/hip_runtime.h>
#include <hip/hip_bf16.h>

#define B_ 8
#define T_ 16
#define D_ 1536
#define N_ 12
#define KH_ 2
#define G_ 6
#define H_ 128
#define S_ 8192
#define NCHUNK 24
#define SPLITS 8
#define SKV 4160   // padded key stride for packed KV (requires CUR+T <= 4160)

typedef __attribute__((ext_vector_type(8))) short bf16x8;
typedef __attribute__((ext_vector_type(4))) float f32x4;
typedef __attribute__((ext_vector_type(4))) unsigned short u16x4;

__device__ __forceinline__ unsigned short f2bf(float x) {
    unsigned u = __float_as_uint(x);
    u += 0x7fffu + ((u >> 16) & 1u);
    return (unsigned short)(u >> 16);
}
__device__ __forceinline__ float bf2f(unsigned short h) {
    return __uint_as_float(((unsigned)h) << 16);
}

// ---------------------------------------------------------------------------
// Split-K MFMA GEMM with split-bf16 (3-product) accuracy. (unchanged)
// ---------------------------------------------------------------------------
__global__ __launch_bounds__(256, 4) void gemm_splitk(
    const float* __restrict__ A,
    const float* __restrict__ W0, int n0, int ldb0,
    const float* __restrict__ W1, int n1, int ldb1,
    const float* __restrict__ W2, int ldb2,
    float* __restrict__ part, int NTOT, int Kdim)
{
    __shared__ __align__(16) unsigned short Ah[64][40], Al[64][40];
    __shared__ __align__(16) unsigned short Bh[64][40], Bl[64][40];
    const int tid = threadIdx.x;
    const int wave = tid >> 6, lane = tid & 63;
    const int col = lane & 15, g = lane >> 4;
    const int row0 = blockIdx.y * 64;
    const int c0 = blockIdx.x * 64;
    const int ks = Kdim / gridDim.z;
    const int k0 = blockIdx.z * ks;

    const float* Bp; int ldb, bc0;
    if (c0 < n0)           { Bp = W0; ldb = ldb0; bc0 = c0; }
    else if (c0 < n0 + n1) { Bp = W1; ldb = ldb1; bc0 = c0 - n0; }
    else                   { Bp = W2; ldb = ldb2; bc0 = c0 - n0 - n1; }

    f32x4 acc[4];
#pragma unroll
    for (int nt = 0; nt < 4; ++nt) acc[nt] = (f32x4){0.f, 0.f, 0.f, 0.f};

    for (int kk = 0; kk < ks; kk += 32) {
        __syncthreads();
        if (tid < 128) {
#pragma unroll
            for (int c = tid; c < 512; c += 128) {
                int r = c >> 3, k4 = c & 7;
                float4 v = *(const float4*)&A[(size_t)(row0 + r) * Kdim + k0 + kk + k4 * 4];
                float f[4] = {v.x, v.y, v.z, v.w};
                u16x4 hv, lv;
#pragma unroll
                for (int i = 0; i < 4; ++i) {
                    unsigned short hh = f2bf(f[i]);
                    hv[i] = hh; lv[i] = f2bf(f[i] - bf2f(hh));
                }
                *(u16x4*)&Ah[r][k4 * 4] = hv;
                *(u16x4*)&Al[r][k4 * 4] = lv;
            }
        } else {
            int t2 = tid - 128;
            int kq = t2 >> 4, cq = t2 & 15;
            float a[4][4];
#pragma unroll
            for (int r = 0; r < 4; ++r) {
                float4 v = *(const float4*)&Bp[(size_t)(k0 + kk + kq * 4 + r) * ldb + bc0 + cq * 4];
                a[r][0] = v.x; a[r][1] = v.y; a[r][2] = v.z; a[r][3] = v.w;
            }
#pragma unroll
            for (int cc = 0; cc < 4; ++cc) {
                u16x4 hv, lv;
#pragma unroll
                for (int r = 0; r < 4; ++r) {
                    unsigned short hh = f2bf(a[r][cc]);
                    hv[r] = hh; lv[r] = f2bf(a[r][cc] - bf2f(hh));
                }
                *(u16x4*)&Bh[cq * 4 + cc][kq * 4] = hv;
                *(u16x4*)&Bl[cq * 4 + cc][kq * 4] = lv;
            }
        }
        __syncthreads();

        bf16x8 ah = *(const bf16x8*)&Ah[wave * 16 + col][g * 8];
        bf16x8 al = *(const bf16x8*)&Al[wave * 16 + col][g * 8];
#pragma unroll
        for (int nt = 0; nt < 4; ++nt) {
            bf16x8 bh = *(const bf16x8*)&Bh[nt * 16 + col][g * 8];
            bf16x8 bl = *(const bf16x8*)&Bl[nt * 16 + col][g * 8];
            acc[nt] = __builtin_amdgcn_mfma_f32_16x16x32_bf16(ah, bh, acc[nt], 0, 0, 0);
            acc[nt] = __builtin_amdgcn_mfma_f32_16x16x32_bf16(ah, bl, acc[nt], 0, 0, 0);
            acc[nt] = __builtin_amdgcn_mfma_f32_16x16x32_bf16(al, bh, acc[nt], 0, 0, 0);
        }
    }
#pragma unroll
    for (int nt = 0; nt < 4; ++nt)
#pragma unroll
        for (int j = 0; j < 4; ++j) {
            size_t prow = (size_t)blockIdx.z * 128 + row0 + wave * 16 + g * 4 + j;
            part[prow * NTOT + c0 + nt * 16 + col] = acc[nt][j];
        }
}

// ---------------------------------------------------------------------------
// Reduce SPLITS partials + bias + RoPE. (unchanged)
// ---------------------------------------------------------------------------
__global__ __launch_bounds__(256) void rope_reduce(
    const float* __restrict__ part,
    const float* __restrict__ bq, const float* __restrict__ bk,
    const float* __restrict__ bv,
    const int* __restrict__ seg, const int* __restrict__ curp,
    float* __restrict__ q_rope, float* __restrict__ k_new,
    float* __restrict__ v_new)
{
    const int row = blockIdx.x;
    const int b = row >> 4, t = row & 15;
    const int tid = threadIdx.x;
    __shared__ float S[2048];
    __shared__ float sc[64][2];

    const int CUR = curp[0];
    int c = 0;
    for (int tt = 0; tt <= t; ++tt) c += (seg[b * T_ + tt] != 0) ? 1 : 0;
    int pos = max(c - 1, 0) + CUR;

    if (tid < 64) {
        float frac = (2.0f * tid) / (float)H_;
        float ts = expf(frac * logf(1000000.0f));
        float ang = (float)pos / ts;
        sc[tid][0] = sinf(ang);
        sc[tid][1] = cosf(ang);
    }
    for (int e = tid; e < 2048; e += 256) {
        float s = 0.f;
#pragma unroll
        for (int sp = 0; sp < SPLITS; ++sp)
            s += part[((size_t)sp * 128 + row) * 2048 + e];
        S[e] = s;
    }
    __syncthreads();

    for (int e = tid; e < 768; e += 256) {
        int n = e >> 6, i = e & 63;
        float x1 = S[n * 128 + i] + bq[n * 128 + i];
        float x2 = S[n * 128 + i + 64] + bq[n * 128 + i + 64];
        float s = sc[i][0], co = sc[i][1];
        q_rope[(size_t)row * 1536 + n * 128 + i]      = x1 * co - x2 * s;
        q_rope[(size_t)row * 1536 + n * 128 + i + 64] = x2 * co + x1 * s;
    }
    if (tid < 128) {
        int n = tid >> 6, i = tid & 63;
        float x1 = S[1536 + n * 128 + i] + bk[n * 128 + i];
        float x2 = S[1536 + n * 128 + i + 64] + bk[n * 128 + i + 64];
        float s = sc[i][0], co = sc[i][1];
        k_new[(size_t)row * 256 + n * 128 + i]      = x1 * co - x2 * s;
        k_new[(size_t)row * 256 + n * 128 + i + 64] = x2 * co + x1 * s;
    }
    v_new[(size_t)row * 256 + tid] = S[1792 + tid] + bv[tid];
}

// ---------------------------------------------------------------------------
// Pack KV to bf16 once: Kb[b][kh][s][128] and Vtb[b][kh][d][s] (transposed).
// (unchanged)
// ---------------------------------------------------------------------------
__global__ __launch_bounds__(256) void pack_kv(
    const float* __restrict__ k_cache, const float* __restrict__ v_cache,
    const float* __restrict__ k_new, const float* __restrict__ v_new,
    const int* __restrict__ curp,
    unsigned short* __restrict__ Kb, unsigned short* __restrict__ Vtb)
{
    const int tile = blockIdx.x, b = blockIdx.y, kh = blockIdx.z;
    const int tid = threadIdx.x;
    const int CUR = curp[0], SPAN = CUR + T_;
    __shared__ float Vs[32][132];
    const int s_base = tile * 32;
    const int rr = tid >> 5, d0 = (tid & 31) * 4;
    const size_t kout = ((size_t)(b * KH_ + kh) * SKV + s_base) * H_;

#pragma unroll
    for (int i = 0; i < 4; ++i) {
        int r = rr + 8 * i;
        int s = min(s_base + r, SPAN - 1);
        const float* kr = (s < CUR)
            ? &k_cache[(((size_t)b * S_ + s) * KH_ + kh) * H_]
            : &k_new[(((size_t)b * T_ + (s - CUR)) * KH_ + kh) * H_];
        const float* vr = (s < CUR)
            ? &v_cache[(((size_t)b * S_ + s) * KH_ + kh) * H_]
            : &v_new[(((size_t)b * T_ + (s - CUR)) * KH_ + kh) * H_];
        float4 kv = *(const float4*)(kr + d0);
        u16x4 hk;
        hk[0] = f2bf(kv.x); hk[1] = f2bf(kv.y); hk[2] = f2bf(kv.z); hk[3] = f2bf(kv.w);
        *(u16x4*)&Kb[kout + (size_t)r * H_ + d0] = hk;
        *(float4*)&Vs[r][d0] = *(const float4*)(vr + d0);
    }
    __syncthreads();

    const int d = tid >> 1, kq = (tid & 1) * 16;
    unsigned short o[16];
#pragma unroll
    for (int i = 0; i < 16; ++i) o[i] = f2bf(Vs[kq + i][d]);
    unsigned short* vp = &Vtb[((size_t)(b * KH_ + kh) * H_ + d) * SKV + s_base + kq];
#pragma unroll
    for (int i = 0; i < 4; ++i)
        *(u16x4*)(vp + i * 4) = *(u16x4*)&o[i * 4];
}

// ---------------------------------------------------------------------------
// MFMA flash attention v9: barrier-free, LDS-free (except 5 KB P relayout).
// (unchanged)
// ---------------------------------------------------------------------------
__global__ __launch_bounds__(256, 3) void attn_mfma(
    const float* __restrict__ q_rope,
    const unsigned short* __restrict__ Kb,
    const unsigned short* __restrict__ Vtb,
    const int* __restrict__ seg, const int* __restrict__ start_ind,
    const int* __restrict__ curp,
    float* __restrict__ part)
{
    const int chunk = blockIdx.x, b = blockIdx.y;
    const int kh = blockIdx.z >> 1, half = blockIdx.z & 1;
    const int tid = threadIdx.x;
    const int wave = tid >> 6, lane = tid & 63;
    const int col = lane & 15, g = lane >> 4;
    const float scale = 0.088388347648318447f;
    const float NEG_INF = -__builtin_inff();

    const int CUR = curp[0];
    const int SPAN = CUR + T_;
    const int CH = (SPAN + NCHUNK - 1) / NCHUNK;
    const int s0 = chunk * CH;
    const int s1 = min(s0 + CH, SPAN);

    int st = start_ind[b];
    if (st < 0) {
        st = 0;
        for (int tt = 0; tt < T_; ++tt)
            if (seg[b * T_ + tt] != 0) { st = tt; break; }
    }

    __shared__ __align__(16) unsigned short Pl[4][16][40];

    const int qbase = half * 64 + wave * 16;
    const int qi_a = min(qbase + col, 95);
    const int t_a = (qi_a * 171) >> 10;
    const int gh_a = qi_a - t_a * G_;
    const float* qp = &q_rope[(((size_t)b * T_ + t_a) * N_ + kh * G_ + gh_a) * H_];
    bf16x8 qf[4];
#pragma unroll
    for (int ks = 0; ks < 4; ++ks) {
        float4 va = *(const float4*)&qp[ks * 32 + g * 8];
        float4 vb = *(const float4*)&qp[ks * 32 + g * 8 + 4];
        float f[8] = {va.x, va.y, va.z, va.w, vb.x, vb.y, vb.z, vb.w};
        union { bf16x8 v; __hip_bfloat162 h2[4]; } W;
#pragma unroll
        for (int i = 0; i < 4; ++i)
            W.h2[i] = __float22bfloat162_rn(make_float2(f[2 * i] * scale, f[2 * i + 1] * scale));
        qf[ks] = W.v;
    }

    int qpos_r[4], segid_r[4];
    bool wrow[4];
#pragma unroll
    for (int j = 0; j < 4; ++j) {
        int qi_raw = qbase + g * 4 + j;
        wrow[j] = (qi_raw < 96);
        int qi_c = min(qi_raw, 95);
        int t_c = (qi_c * 171) >> 10;
        segid_r[j] = seg[b * T_ + t_c];
        qpos_r[j] = CUR + t_c - st;
    }

    float m[4], lsum[4];
#pragma unroll
    for (int j = 0; j < 4; ++j) { m[j] = NEG_INF; lsum[j] = 0.f; }
    f32x4 oacc[8];
#pragma unroll
    for (int nt = 0; nt < 8; ++nt) oacc[nt] = (f32x4){0.f, 0.f, 0.f, 0.f};

    const unsigned short* Kbase = Kb + (size_t)(b * KH_ + kh) * SKV * H_;
    const unsigned short* Vbase = Vtb + (size_t)(b * KH_ + kh) * H_ * SKV;

    auto loadK = [&](bf16x8* kf, int stile) {
#pragma unroll
        for (int kt = 0; kt < 2; ++kt)
#pragma unroll
            for (int ks = 0; ks < 4; ++ks)
                kf[kt * 4 + ks] = *(const bf16x8*)
                    &Kbase[(size_t)(stile + kt * 16 + col) * H_ + ks * 32 + g * 8];
    };

    auto computeTile = [&](const bf16x8* kf, int stile) {
        f32x4 sacc0 = {0.f, 0.f, 0.f, 0.f}, sacc1 = {0.f, 0.f, 0.f, 0.f};
#pragma unroll
        for (int ks = 0; ks < 4; ++ks) {
            sacc0 = __builtin_amdgcn_mfma_f32_16x16x32_bf16(qf[ks], kf[ks], sacc0, 0, 0, 0);
            sacc1 = __builtin_amdgcn_mfma_f32_16x16x32_bf16(qf[ks], kf[4 + ks], sacc1, 0, 0, 0);
        }

        float rj[4];
        const int skey0 = stile + col, skey1 = stile + 16 + col;
#pragma unroll
        for (int j = 0; j < 4; ++j) {
            bool v0 = (skey0 < s1) && (skey0 - st <= qpos_r[j]) &&
                      (((skey0 >= st) ? 1 : 0) == segid_r[j]);
            bool v1 = (skey1 < s1) && (skey1 - st <= qpos_r[j]) &&
                      (((skey1 >= st) ? 1 : 0) == segid_r[j]);
            float lg0 = v0 ? sacc0[j] : NEG_INF;
            float lg1 = v1 ? sacc1[j] : NEG_INF;
            float tm = fmaxf(lg0, lg1);
            tm = fmaxf(tm, __shfl_xor(tm, 1));
            tm = fmaxf(tm, __shfl_xor(tm, 2));
            tm = fmaxf(tm, __shfl_xor(tm, 4));
            tm = fmaxf(tm, __shfl_xor(tm, 8));
            float mn = fmaxf(m[j], tm);
            float r, p0, p1;
            if (mn == NEG_INF) { r = 1.f; p0 = 0.f; p1 = 0.f; }
            else {
                r  = __expf(m[j] - mn);
                p0 = __expf(lg0 - mn);
                p1 = __expf(lg1 - mn);
            }
            float ps = p0 + p1;
            ps += __shfl_xor(ps, 1);
            ps += __shfl_xor(ps, 2);
            ps += __shfl_xor(ps, 4);
            ps += __shfl_xor(ps, 8);
            lsum[j] = lsum[j] * r + ps;
            m[j] = mn;
            rj[j] = r;
            int row = g * 4 + j;
            Pl[wave][row][col]      = f2bf(p0);
            Pl[wave][row][16 + col] = f2bf(p1);
        }

#pragma unroll
        for (int nt = 0; nt < 8; ++nt) {
#pragma unroll
            for (int j = 0; j < 4; ++j) oacc[nt][j] *= rj[j];
        }

        bf16x8 pa = *(const bf16x8*)&Pl[wave][col][g * 8];
#pragma unroll
        for (int nt = 0; nt < 8; ++nt) {
            bf16x8 vb = *(const bf16x8*)
                &Vbase[(size_t)(nt * 16 + col) * SKV + stile + g * 8];
            oacc[nt] = __builtin_amdgcn_mfma_f32_16x16x32_bf16(pa, vb, oacc[nt], 0, 0, 0);
        }
    };

    const int ntiles = (s1 - s0 + 31) >> 5;
    bf16x8 kfA[8], kfB[8];
    loadK(kfA, s0);
    for (int ti = 0; ti < ntiles; ti += 2) {
        if (ti + 1 < ntiles) loadK(kfB, s0 + (ti + 1) * 32);
        computeTile(kfA, s0 + ti * 32);
        if (ti + 1 < ntiles) {
            if (ti + 2 < ntiles) loadK(kfA, s0 + (ti + 2) * 32);
            computeTile(kfB, s0 + (ti + 1) * 32);
        }
    }

    const size_t base_q = (((size_t)chunk * B_ + b) * KH_ + kh) * 96;
#pragma unroll
    for (int j = 0; j < 4; ++j) {
        if (!wrow[j]) continue;
        int qi = qbase + g * 4 + j;
        size_t pb = (base_q + qi) * 132;
        if (col == 0) { part[pb] = m[j]; part[pb + 1] = lsum[j]; }
#pragma unroll
        for (int nt = 0; nt < 8; ++nt)
            part[pb + 2 + nt * 16 + col] = oacc[nt][j];
    }
}

// ---------------------------------------------------------------------------
// Combine v2: one block per (qi, b, kh); 128 threads = one per output dim.
// m/l staged in LDS by first NCHUNK lanes; num-loads are coalesced 512B
// segments, NCHUNK independent streams in flight. 1536 blocks.
// ---------------------------------------------------------------------------
__global__ __launch_bounds__(128) void combine_kernel(
    const float* __restrict__ part, float* __restrict__ qkv)
{
    const int qi = blockIdx.x, b = blockIdx.y, kh = blockIdx.z;
    const int h = threadIdx.x;
    const size_t cstride = (size_t)B_ * KH_ * 96 * 132;
    const size_t base0 = (((size_t)b * KH_ + kh) * 96 + qi) * 132;

    __shared__ float sm[NCHUNK], sl[NCHUNK];
    if (h < NCHUNK) {
        sm[h] = part[base0 + (size_t)h * cstride];
        sl[h] = part[base0 + (size_t)h * cstride + 1];
    }
    __syncthreads();

    float M = -__builtin_inff();
#pragma unroll
    for (int c = 0; c < NCHUNK; ++c) M = fmaxf(M, sm[c]);

    float den = 0.f, num = 0.f;
#pragma unroll
    for (int c = 0; c < NCHUNK; ++c) {
        float mc = sm[c];
        float e = (M == -__builtin_inff() || mc == -__builtin_inff())
                      ? 0.f : __expf(mc - M);
        den += e * sl[c];
        num += e * part[base0 + (size_t)c * cstride + 2 + h];
    }

    const int t = (qi * 171) >> 10;          // qi/6
    const int g = qi - t * G_;
    const int n = kh * G_ + g;
    qkv[(((size_t)b * T_ + t) * N_ + n) * H_ + h] = (den > 0.f) ? num / den : 0.f;
}

// ---------------------------------------------------------------------------
__global__ __launch_bounds__(256) void sum_reduce(
    const float* __restrict__ part, float* __restrict__ out, int n)
{
    int i = blockIdx.x * 256 + threadIdx.x;
    if (i < n) {
        float s = 0.f;
#pragma unroll
        for (int sp = 0; sp < SPLITS; ++sp) s += part[(size_t)sp * n + i];
        out[i] = s;
    }
}

// ---------------------------------------------------------------------------
extern "C" void kernel_launch(void* const* d_in, const int* in_sizes, int n_in,
                              void* d_out, int out_size, void* d_ws, size_t ws_size,
                              hipStream_t stream)
{
    (void)in_sizes; (void)n_in; (void)out_size; (void)ws_size;
    const float* x       = (const float*)d_in[0];
    const float* k_cache = (const float*)d_in[1];
    const float* v_cache = (const float*)d_in[2];
    const float* wq      = (const float*)d_in[3];
    const float* bq      = (const float*)d_in[4];
    const float* wk      = (const float*)d_in[5];
    const float* bk      = (const float*)d_in[6];
    const float* wv      = (const float*)d_in[7];
    const float* bv      = (const float*)d_in[8];
    const float* wo      = (const float*)d_in[9];
    const int*   seg     = (const int*)d_in[10];
    const int*   start_i = (const int*)d_in[11];
    const int*   curp    = (const int*)d_in[12];
    float* out = (float*)d_out;
    float* ws  = (float*)d_ws;

    const size_t PSZ  = (size_t)NCHUNK * B_ * KH_ * 96 * 132; // 4,866,048
    const size_t QSZ  = (size_t)B_ * T_ * N_ * H_;            // 196,608
    const size_t KSZ  = (size_t)B_ * T_ * KH_ * H_;           // 32,768
    float* partP  = ws;
    float* partA  = ws;
    float* q_rope = ws + PSZ;
    float* k_new  = q_rope + QSZ;
    float* v_new  = k_new + KSZ;
    float* qkv    = v_new + KSZ;
    unsigned short* kvb = (unsigned short*)(qkv + QSZ);
    unsigned short* Kb  = kvb;
    unsigned short* Vtb = kvb + (size_t)B_ * KH_ * SKV * H_;  // 8,517,120

    gemm_splitk<<<dim3(32, 2, SPLITS), 256, 0, stream>>>(
        x, wq, 1536, 1536, wk, 256, 256, wv, 256, partP, 2048, D_);

    rope_reduce<<<B_ * T_, 256, 0, stream>>>(partP, bq, bk, bv, seg, curp,
                                             q_rope, k_new, v_new);

    pack_kv<<<dim3(SKV / 32, B_, KH_), 256, 0, stream>>>(
        k_cache, v_cache, k_new, v_new, curp, Kb, Vtb);

    attn_mfma<<<dim3(NCHUNK, B_, KH_ * 2), 256, 0, stream>>>(
        q_rope, Kb, Vtb, seg, start_i, curp, partA);

    combine_kernel<<<dim3(96, B_, KH_), 128, 0, stream>>>(partA, qkv);

    gemm_splitk<<<dim3(24, 2, SPLITS), 256, 0, stream>>>(
        qkv, wo, 1536, 1536, wo, 0, 1536, wo, 1536, partP, 1536, N_ * H_);

    sum_reduce<<<(B_ * T_ * D_ + 255) / 256, 256, 0, stream>>>(
        partP, out, B_ * T_ * D_);
}

// Round 11
// 99.861 us; speedup vs baseline: 1.7300x; 1.1242x over previous
//
#include <hip/hip_runtime.h>
#include <hip/hip_bf16.h>

#define B_ 8
#define T_ 16
#define D_ 1536
#define N_ 12
#define KH_ 2
#define G_ 6
#define H_ 128
#define S_ 8192
#define NCHUNK 24
#define SPLITS 8
#define SKV 4160           // padded key capacity (CUR+T <= 4160)
#define NTILE (SKV / 32)   // 130 packed tiles per (b,kh)
#define TILE_USH 8192      // per-tile ushorts: K frags 4096 + V frags 4096

typedef __attribute__((ext_vector_type(8))) short bf16x8;
typedef __attribute__((ext_vector_type(4))) float f32x4;
typedef __attribute__((ext_vector_type(4))) unsigned short u16x4;

__device__ __forceinline__ unsigned short f2bf(float x) {
    unsigned u = __float_as_uint(x);
    u += 0x7fffu + ((u >> 16) & 1u);
    return (unsigned short)(u >> 16);
}
__device__ __forceinline__ float bf2f(unsigned short h) {
    return __uint_as_float(((unsigned)h) << 16);
}

// ---------------------------------------------------------------------------
// Split-K MFMA GEMM with split-bf16 (3-product) accuracy. (unchanged)
// ---------------------------------------------------------------------------
__global__ __launch_bounds__(256, 4) void gemm_splitk(
    const float* __restrict__ A,
    const float* __restrict__ W0, int n0, int ldb0,
    const float* __restrict__ W1, int n1, int ldb1,
    const float* __restrict__ W2, int ldb2,
    float* __restrict__ part, int NTOT, int Kdim)
{
    __shared__ __align__(16) unsigned short Ah[64][40], Al[64][40];
    __shared__ __align__(16) unsigned short Bh[64][40], Bl[64][40];
    const int tid = threadIdx.x;
    const int wave = tid >> 6, lane = tid & 63;
    const int col = lane & 15, g = lane >> 4;
    const int row0 = blockIdx.y * 64;
    const int c0 = blockIdx.x * 64;
    const int ks = Kdim / gridDim.z;
    const int k0 = blockIdx.z * ks;

    const float* Bp; int ldb, bc0;
    if (c0 < n0)           { Bp = W0; ldb = ldb0; bc0 = c0; }
    else if (c0 < n0 + n1) { Bp = W1; ldb = ldb1; bc0 = c0 - n0; }
    else                   { Bp = W2; ldb = ldb2; bc0 = c0 - n0 - n1; }

    f32x4 acc[4];
#pragma unroll
    for (int nt = 0; nt < 4; ++nt) acc[nt] = (f32x4){0.f, 0.f, 0.f, 0.f};

    for (int kk = 0; kk < ks; kk += 32) {
        __syncthreads();
        if (tid < 128) {
#pragma unroll
            for (int c = tid; c < 512; c += 128) {
                int r = c >> 3, k4 = c & 7;
                float4 v = *(const float4*)&A[(size_t)(row0 + r) * Kdim + k0 + kk + k4 * 4];
                float f[4] = {v.x, v.y, v.z, v.w};
                u16x4 hv, lv;
#pragma unroll
                for (int i = 0; i < 4; ++i) {
                    unsigned short hh = f2bf(f[i]);
                    hv[i] = hh; lv[i] = f2bf(f[i] - bf2f(hh));
                }
                *(u16x4*)&Ah[r][k4 * 4] = hv;
                *(u16x4*)&Al[r][k4 * 4] = lv;
            }
        } else {
            int t2 = tid - 128;
            int kq = t2 >> 4, cq = t2 & 15;
            float a[4][4];
#pragma unroll
            for (int r = 0; r < 4; ++r) {
                float4 v = *(const float4*)&Bp[(size_t)(k0 + kk + kq * 4 + r) * ldb + bc0 + cq * 4];
                a[r][0] = v.x; a[r][1] = v.y; a[r][2] = v.z; a[r][3] = v.w;
            }
#pragma unroll
            for (int cc = 0; cc < 4; ++cc) {
                u16x4 hv, lv;
#pragma unroll
                for (int r = 0; r < 4; ++r) {
                    unsigned short hh = f2bf(a[r][cc]);
                    hv[r] = hh; lv[r] = f2bf(a[r][cc] - bf2f(hh));
                }
                *(u16x4*)&Bh[cq * 4 + cc][kq * 4] = hv;
                *(u16x4*)&Bl[cq * 4 + cc][kq * 4] = lv;
            }
        }
        __syncthreads();

        bf16x8 ah = *(const bf16x8*)&Ah[wave * 16 + col][g * 8];
        bf16x8 al = *(const bf16x8*)&Al[wave * 16 + col][g * 8];
#pragma unroll
        for (int nt = 0; nt < 4; ++nt) {
            bf16x8 bh = *(const bf16x8*)&Bh[nt * 16 + col][g * 8];
            bf16x8 bl = *(const bf16x8*)&Bl[nt * 16 + col][g * 8];
            acc[nt] = __builtin_amdgcn_mfma_f32_16x16x32_bf16(ah, bh, acc[nt], 0, 0, 0);
            acc[nt] = __builtin_amdgcn_mfma_f32_16x16x32_bf16(ah, bl, acc[nt], 0, 0, 0);
            acc[nt] = __builtin_amdgcn_mfma_f32_16x16x32_bf16(al, bh, acc[nt], 0, 0, 0);
        }
    }
#pragma unroll
    for (int nt = 0; nt < 4; ++nt)
#pragma unroll
        for (int j = 0; j < 4; ++j) {
            size_t prow = (size_t)blockIdx.z * 128 + row0 + wave * 16 + g * 4 + j;
            part[prow * NTOT + c0 + nt * 16 + col] = acc[nt][j];
        }
}

// ---------------------------------------------------------------------------
// Reduce SPLITS partials + bias + RoPE. (unchanged)
// ---------------------------------------------------------------------------
__global__ __launch_bounds__(256) void rope_reduce(
    const float* __restrict__ part,
    const float* __restrict__ bq, const float* __restrict__ bk,
    const float* __restrict__ bv,
    const int* __restrict__ seg, const int* __restrict__ curp,
    float* __restrict__ q_rope, float* __restrict__ k_new,
    float* __restrict__ v_new)
{
    const int row = blockIdx.x;
    const int b = row >> 4, t = row & 15;
    const int tid = threadIdx.x;
    __shared__ float S[2048];
    __shared__ float sc[64][2];

    const int CUR = curp[0];
    int c = 0;
    for (int tt = 0; tt <= t; ++tt) c += (seg[b * T_ + tt] != 0) ? 1 : 0;
    int pos = max(c - 1, 0) + CUR;

    if (tid < 64) {
        float frac = (2.0f * tid) / (float)H_;
        float ts = expf(frac * logf(1000000.0f));
        float ang = (float)pos / ts;
        sc[tid][0] = sinf(ang);
        sc[tid][1] = cosf(ang);
    }
    for (int e = tid; e < 2048; e += 256) {
        float s = 0.f;
#pragma unroll
        for (int sp = 0; sp < SPLITS; ++sp)
            s += part[((size_t)sp * 128 + row) * 2048 + e];
        S[e] = s;
    }
    __syncthreads();

    for (int e = tid; e < 768; e += 256) {
        int n = e >> 6, i = e & 63;
        float x1 = S[n * 128 + i] + bq[n * 128 + i];
        float x2 = S[n * 128 + i + 64] + bq[n * 128 + i + 64];
        float s = sc[i][0], co = sc[i][1];
        q_rope[(size_t)row * 1536 + n * 128 + i]      = x1 * co - x2 * s;
        q_rope[(size_t)row * 1536 + n * 128 + i + 64] = x2 * co + x1 * s;
    }
    if (tid < 128) {
        int n = tid >> 6, i = tid & 63;
        float x1 = S[1536 + n * 128 + i] + bk[n * 128 + i];
        float x2 = S[1536 + n * 128 + i + 64] + bk[n * 128 + i + 64];
        float s = sc[i][0], co = sc[i][1];
        k_new[(size_t)row * 256 + n * 128 + i]      = x1 * co - x2 * s;
        k_new[(size_t)row * 256 + n * 128 + i + 64] = x2 * co + x1 * s;
    }
    v_new[(size_t)row * 256 + tid] = S[1792 + tid] + bv[tid];
}

// ---------------------------------------------------------------------------
// Pack KV v2: write bf16 MFMA FRAGMENTS in lane order so attention loads are
// fully coalesced (16B/lane x 64 lanes = 1KB bursts).
// Per 32-key tile: KT[f][lane][8]  f=kt*4+ks: elem e = K[kt*16+(l&15)][ks*32+(l>>4)*8+e]
//                  VT[f][lane][8]  f=nt:      elem e = V[(l>>4)*8+e][nt*16+(l&15)]
// grid = (NTILE, B, KH), 256 threads; tile staged through LDS f32 first.
// ---------------------------------------------------------------------------
__global__ __launch_bounds__(256) void pack_kv(
    const float* __restrict__ k_cache, const float* __restrict__ v_cache,
    const float* __restrict__ k_new, const float* __restrict__ v_new,
    const int* __restrict__ curp,
    unsigned short* __restrict__ KVf)
{
    const int tile = blockIdx.x, b = blockIdx.y, kh = blockIdx.z;
    const int tid = threadIdx.x;
    const int CUR = curp[0], SPAN = CUR + T_;
    __shared__ float Ks[32][133], Vsh[32][133];
    const int s_base = tile * 32;
    const int rr = tid >> 5, d0 = (tid & 31) * 4;

#pragma unroll
    for (int i = 0; i < 4; ++i) {
        int r = rr + 8 * i;
        int s = min(s_base + r, SPAN - 1);
        const float* kr = (s < CUR)
            ? &k_cache[(((size_t)b * S_ + s) * KH_ + kh) * H_]
            : &k_new[(((size_t)b * T_ + (s - CUR)) * KH_ + kh) * H_];
        const float* vr = (s < CUR)
            ? &v_cache[(((size_t)b * S_ + s) * KH_ + kh) * H_]
            : &v_new[(((size_t)b * T_ + (s - CUR)) * KH_ + kh) * H_];
        *(float4*)&Ks[r][d0]  = *(const float4*)(kr + d0);
        *(float4*)&Vsh[r][d0] = *(const float4*)(vr + d0);
    }
    __syncthreads();

    unsigned short* KT = KVf + ((size_t)(b * KH_ + kh) * NTILE + tile) * TILE_USH;
    unsigned short* VT = KT + 4096;

#pragma unroll
    for (int hw = 0; hw < 2; ++hw) {
        const int w = tid + hw * 256;
        const int f = w >> 6, l = w & 63;
        const int col = l & 15, g = l >> 4;
        // K fragment
        {
            const int key = (f >> 2) * 16 + col;
            const int dim = (f & 3) * 32 + g * 8;
            u16x4 o0, o1;
#pragma unroll
            for (int e = 0; e < 4; ++e) {
                o0[e] = f2bf(Ks[key][dim + e]);
                o1[e] = f2bf(Ks[key][dim + 4 + e]);
            }
            *(u16x4*)&KT[(size_t)w * 8]     = o0;
            *(u16x4*)&KT[(size_t)w * 8 + 4] = o1;
        }
        // V fragment
        {
            const int dim = f * 16 + col;
            u16x4 o0, o1;
#pragma unroll
            for (int e = 0; e < 4; ++e) {
                o0[e] = f2bf(Vsh[g * 8 + e][dim]);
                o1[e] = f2bf(Vsh[g * 8 + 4 + e][dim]);
            }
            *(u16x4*)&VT[(size_t)w * 8]     = o0;
            *(u16x4*)&VT[(size_t)w * 8 + 4] = o1;
        }
    }
}

// ---------------------------------------------------------------------------
// MFMA flash attention v10: barrier-free, fragment-packed coalesced KV.
// grid = (NCHUNK, B, KH*2 q-halves), 256 thr = 4 waves.
// Chunk span CH rounded to multiple of 32 so chunks align with packed tiles.
// K dbuf in named registers; V frags hoisted to top of tile (QK+softmax cover).
// ---------------------------------------------------------------------------
__global__ __launch_bounds__(256, 3) void attn_mfma(
    const float* __restrict__ q_rope,
    const unsigned short* __restrict__ KVf,
    const int* __restrict__ seg, const int* __restrict__ start_ind,
    const int* __restrict__ curp,
    float* __restrict__ part)
{
    const int chunk = blockIdx.x, b = blockIdx.y;
    const int kh = blockIdx.z >> 1, half = blockIdx.z & 1;
    const int tid = threadIdx.x;
    const int wave = tid >> 6, lane = tid & 63;
    const int col = lane & 15, g = lane >> 4;
    const float scale = 0.088388347648318447f;
    const float NEG_INF = -__builtin_inff();

    const int CUR = curp[0];
    const int SPAN = CUR + T_;
    const int CH = (((SPAN + NCHUNK - 1) / NCHUNK) + 31) & ~31;  // multiple of 32
    const int s0 = chunk * CH;
    const int s1 = min(s0 + CH, SPAN);

    int st = start_ind[b];
    if (st < 0) {
        st = 0;
        for (int tt = 0; tt < T_; ++tt)
            if (seg[b * T_ + tt] != 0) { st = tt; break; }
    }

    __shared__ __align__(16) unsigned short Pl[4][16][40];

    const int qbase = half * 64 + wave * 16;
    const int qi_a = min(qbase + col, 95);
    const int t_a = (qi_a * 171) >> 10;
    const int gh_a = qi_a - t_a * G_;
    const float* qp = &q_rope[(((size_t)b * T_ + t_a) * N_ + kh * G_ + gh_a) * H_];
    bf16x8 qf[4];
#pragma unroll
    for (int ks = 0; ks < 4; ++ks) {
        float4 va = *(const float4*)&qp[ks * 32 + g * 8];
        float4 vb = *(const float4*)&qp[ks * 32 + g * 8 + 4];
        float f[8] = {va.x, va.y, va.z, va.w, vb.x, vb.y, vb.z, vb.w};
        union { bf16x8 v; __hip_bfloat162 h2[4]; } W;
#pragma unroll
        for (int i = 0; i < 4; ++i)
            W.h2[i] = __float22bfloat162_rn(make_float2(f[2 * i] * scale, f[2 * i + 1] * scale));
        qf[ks] = W.v;
    }

    int qpos_r[4], segid_r[4];
    bool wrow[4];
#pragma unroll
    for (int j = 0; j < 4; ++j) {
        int qi_raw = qbase + g * 4 + j;
        wrow[j] = (qi_raw < 96);
        int qi_c = min(qi_raw, 95);
        int t_c = (qi_c * 171) >> 10;
        segid_r[j] = seg[b * T_ + t_c];
        qpos_r[j] = CUR + t_c - st;
    }

    float m[4], lsum[4];
#pragma unroll
    for (int j = 0; j < 4; ++j) { m[j] = NEG_INF; lsum[j] = 0.f; }
    f32x4 oacc[8];
#pragma unroll
    for (int nt = 0; nt < 8; ++nt) oacc[nt] = (f32x4){0.f, 0.f, 0.f, 0.f};

    const unsigned short* KVbase = KVf + (size_t)(b * KH_ + kh) * NTILE * TILE_USH;

    auto loadK = [&](bf16x8* kf, int tileIdx) {
        const unsigned short* KT = KVbase + (size_t)tileIdx * TILE_USH;
#pragma unroll
        for (int f = 0; f < 8; ++f)
            kf[f] = *(const bf16x8*)&KT[(f * 64 + lane) * 8];   // coalesced 1KB
    };

    auto computeTile = [&](const bf16x8* kf, int tileIdx, int stile) {
        // V fragments first: QK + softmax cover their latency
        const unsigned short* VT = KVbase + (size_t)tileIdx * TILE_USH + 4096;
        bf16x8 vfr[8];
#pragma unroll
        for (int f = 0; f < 8; ++f)
            vfr[f] = *(const bf16x8*)&VT[(f * 64 + lane) * 8];  // coalesced 1KB

        f32x4 sacc0 = {0.f, 0.f, 0.f, 0.f}, sacc1 = {0.f, 0.f, 0.f, 0.f};
#pragma unroll
        for (int ks = 0; ks < 4; ++ks) {
            sacc0 = __builtin_amdgcn_mfma_f32_16x16x32_bf16(qf[ks], kf[ks], sacc0, 0, 0, 0);
            sacc1 = __builtin_amdgcn_mfma_f32_16x16x32_bf16(qf[ks], kf[4 + ks], sacc1, 0, 0, 0);
        }

        float rj[4];
        const int skey0 = stile + col, skey1 = stile + 16 + col;
#pragma unroll
        for (int j = 0; j < 4; ++j) {
            bool v0 = (skey0 < s1) && (skey0 - st <= qpos_r[j]) &&
                      (((skey0 >= st) ? 1 : 0) == segid_r[j]);
            bool v1 = (skey1 < s1) && (skey1 - st <= qpos_r[j]) &&
                      (((skey1 >= st) ? 1 : 0) == segid_r[j]);
            float lg0 = v0 ? sacc0[j] : NEG_INF;
            float lg1 = v1 ? sacc1[j] : NEG_INF;
            float tm = fmaxf(lg0, lg1);
            tm = fmaxf(tm, __shfl_xor(tm, 1));
            tm = fmaxf(tm, __shfl_xor(tm, 2));
            tm = fmaxf(tm, __shfl_xor(tm, 4));
            tm = fmaxf(tm, __shfl_xor(tm, 8));
            float mn = fmaxf(m[j], tm);
            float r, p0, p1;
            if (mn == NEG_INF) { r = 1.f; p0 = 0.f; p1 = 0.f; }
            else {
                r  = __expf(m[j] - mn);
                p0 = __expf(lg0 - mn);
                p1 = __expf(lg1 - mn);
            }
            float ps = p0 + p1;
            ps += __shfl_xor(ps, 1);
            ps += __shfl_xor(ps, 2);
            ps += __shfl_xor(ps, 4);
            ps += __shfl_xor(ps, 8);
            lsum[j] = lsum[j] * r + ps;
            m[j] = mn;
            rj[j] = r;
            int row = g * 4 + j;
            Pl[wave][row][col]      = f2bf(p0);
            Pl[wave][row][16 + col] = f2bf(p1);
        }

#pragma unroll
        for (int nt = 0; nt < 8; ++nt) {
#pragma unroll
            for (int j = 0; j < 4; ++j) oacc[nt][j] *= rj[j];
        }

        bf16x8 pa = *(const bf16x8*)&Pl[wave][col][g * 8];
#pragma unroll
        for (int nt = 0; nt < 8; ++nt)
            oacc[nt] = __builtin_amdgcn_mfma_f32_16x16x32_bf16(pa, vfr[nt], oacc[nt], 0, 0, 0);
    };

    const int nt_raw = (s1 - s0 + 31) >> 5;
    const int ntiles = (s1 > s0) ? nt_raw : 0;
    const int tile0 = s0 >> 5;
    bf16x8 kfA[8], kfB[8];
    if (ntiles > 0) loadK(kfA, tile0);
    for (int ti = 0; ti < ntiles; ti += 2) {
        if (ti + 1 < ntiles) loadK(kfB, tile0 + ti + 1);
        computeTile(kfA, tile0 + ti, s0 + ti * 32);
        if (ti + 1 < ntiles) {
            if (ti + 2 < ntiles) loadK(kfA, tile0 + ti + 2);
            computeTile(kfB, tile0 + ti + 1, s0 + (ti + 1) * 32);
        }
    }

    const size_t base_q = (((size_t)chunk * B_ + b) * KH_ + kh) * 96;
#pragma unroll
    for (int j = 0; j < 4; ++j) {
        if (!wrow[j]) continue;
        int qi = qbase + g * 4 + j;
        size_t pb = (base_q + qi) * 132;
        if (col == 0) { part[pb] = m[j]; part[pb + 1] = lsum[j]; }
#pragma unroll
        for (int nt = 0; nt < 8; ++nt)
            part[pb + 2 + nt * 16 + col] = oacc[nt][j];
    }
}

// ---------------------------------------------------------------------------
// Combine v2 (unchanged): one block per (qi, b, kh).
// ---------------------------------------------------------------------------
__global__ __launch_bounds__(128) void combine_kernel(
    const float* __restrict__ part, float* __restrict__ qkv)
{
    const int qi = blockIdx.x, b = blockIdx.y, kh = blockIdx.z;
    const int h = threadIdx.x;
    const size_t cstride = (size_t)B_ * KH_ * 96 * 132;
    const size_t base0 = (((size_t)b * KH_ + kh) * 96 + qi) * 132;

    __shared__ float sm[NCHUNK], sl[NCHUNK];
    if (h < NCHUNK) {
        sm[h] = part[base0 + (size_t)h * cstride];
        sl[h] = part[base0 + (size_t)h * cstride + 1];
    }
    __syncthreads();

    float M = -__builtin_inff();
#pragma unroll
    for (int c = 0; c < NCHUNK; ++c) M = fmaxf(M, sm[c]);

    float den = 0.f, num = 0.f;
#pragma unroll
    for (int c = 0; c < NCHUNK; ++c) {
        float mc = sm[c];
        float e = (M == -__builtin_inff() || mc == -__builtin_inff())
                      ? 0.f : __expf(mc - M);
        den += e * sl[c];
        num += e * part[base0 + (size_t)c * cstride + 2 + h];
    }

    const int t = (qi * 171) >> 10;
    const int g = qi - t * G_;
    const int n = kh * G_ + g;
    qkv[(((size_t)b * T_ + t) * N_ + n) * H_ + h] = (den > 0.f) ? num / den : 0.f;
}

// ---------------------------------------------------------------------------
__global__ __launch_bounds__(256) void sum_reduce(
    const float* __restrict__ part, float* __restrict__ out, int n)
{
    int i = blockIdx.x * 256 + threadIdx.x;
    if (i < n) {
        float s = 0.f;
#pragma unroll
        for (int sp = 0; sp < SPLITS; ++sp) s += part[(size_t)sp * n + i];
        out[i] = s;
    }
}

// ---------------------------------------------------------------------------
extern "C" void kernel_launch(void* const* d_in, const int* in_sizes, int n_in,
                              void* d_out, int out_size, void* d_ws, size_t ws_size,
                              hipStream_t stream)
{
    (void)in_sizes; (void)n_in; (void)out_size; (void)ws_size;
    const float* x       = (const float*)d_in[0];
    const float* k_cache = (const float*)d_in[1];
    const float* v_cache = (const float*)d_in[2];
    const float* wq      = (const float*)d_in[3];
    const float* bq      = (const float*)d_in[4];
    const float* wk      = (const float*)d_in[5];
    const float* bk      = (const float*)d_in[6];
    const float* wv      = (const float*)d_in[7];
    const float* bv      = (const float*)d_in[8];
    const float* wo      = (const float*)d_in[9];
    const int*   seg     = (const int*)d_in[10];
    const int*   start_i = (const int*)d_in[11];
    const int*   curp    = (const int*)d_in[12];
    float* out = (float*)d_out;
    float* ws  = (float*)d_ws;

    const size_t PSZ  = (size_t)NCHUNK * B_ * KH_ * 96 * 132; // 4,866,048
    const size_t QSZ  = (size_t)B_ * T_ * N_ * H_;            // 196,608
    const size_t KSZ  = (size_t)B_ * T_ * KH_ * H_;           // 32,768
    float* partP  = ws;
    float* partA  = ws;
    float* q_rope = ws + PSZ;
    float* k_new  = q_rope + QSZ;
    float* v_new  = k_new + KSZ;
    float* qkv    = v_new + KSZ;
    unsigned short* KVf = (unsigned short*)(qkv + QSZ);       // 17,039,360 ushorts

    gemm_splitk<<<dim3(32, 2, SPLITS), 256, 0, stream>>>(
        x, wq, 1536, 1536, wk, 256, 256, wv, 256, partP, 2048, D_);

    rope_reduce<<<B_ * T_, 256, 0, stream>>>(partP, bq, bk, bv, seg, curp,
                                             q_rope, k_new, v_new);

    pack_kv<<<dim3(NTILE, B_, KH_), 256, 0, stream>>>(
        k_cache, v_cache, k_new, v_new, curp, KVf);

    attn_mfma<<<dim3(NCHUNK, B_, KH_ * 2), 256, 0, stream>>>(
        q_rope, KVf, seg, start_i, curp, partA);

    combine_kernel<<<dim3(96, B_, KH_), 128, 0, stream>>>(partA, qkv);

    gemm_splitk<<<dim3(24, 2, SPLITS), 256, 0, stream>>>(
        qkv, wo, 1536, 1536, wo, 0, 1536, wo, 1536, partP, 1536, N_ * H_);

    sum_reduce<<<(B_ * T_ * D_ + 255) / 256, 256, 0, stream>>>(
        partP, out, B_ * T_ * D_);
}